// Round 10
// baseline (396.924 us; speedup 1.0000x reference)
//
#include <hip/hip_runtime.h>
#include <math.h>
#include <float.h>

#define L_   4096
#define M_   8192
#define H_   8
#define D_   64
#define KK   45          // 5 * ceil(ln(4096))

// ws layout in float2 units
#define WS_C   0         // c[4096]  : e^{-i pi j^2 / 8191}
#define WS_D   4096      // d[4096]  : e^{+i pi j^2 / 8190}
#define WS_TW  8192      // tw[8192] : e^{-2 pi i j / 8192} (fp64-accurate; setup_filters only)
#define WS_H1  16384     // H1s[8192]: DIF-FFT(conj-chirp c), pre-scaled 1/8192, digit-reversed
#define WS_H2  24576     // H2s[8192]: same for d
#define WS_QKV 32768     // float2 offset where staged q/k/v planes start
// tables: 256 KB; then q/k/v planes: 3 x 1M floats = 12 MB

typedef float vf4 __attribute__((ext_vector_type(4)));   // true vector type: OK for nontemporal builtins

__device__ __forceinline__ float2 cadd(float2 a, float2 b) { return make_float2(a.x + b.x, a.y + b.y); }
__device__ __forceinline__ float2 csub(float2 a, float2 b) { return make_float2(a.x - b.x, a.y - b.y); }
__device__ __forceinline__ float2 cmulf(float2 a, float2 b) {
  return make_float2(a.x * b.x - a.y * b.y, a.x * b.y + a.y * b.x);
}
__device__ __forceinline__ float2 cmulcf(float2 a, float2 b) {  // a * conj(b)
  return make_float2(a.x * b.x + a.y * b.y, a.y * b.x - a.x * b.y);
}

// register twiddle: e^{-2 pi i e / 8192}, e in [0, 2048)
__device__ __forceinline__ float2 twf(int e) {
  float s, c;
  __sincosf((float)e * -7.66990394e-4f, &s, &c);   // -2*pi/8192
  return make_float2(c, s);
}

// LDS bank swizzle (main kernel only): bijective, preserves bit0 (float2-pair adjacency).
// PS is GF(2)-linear: PS(a^b) = PS(a)^PS(b), and i0+kq == i0^kq (bit-disjoint), so
// per-stage offsets are compile-time XORs.
// CONSISTENCY (r9 bugfix): pair {2t,2t+1} -> {PS(2t), PS(2t)+1} requires
// PS4(t) = t ^ ((t>>3)&7), since ((t>>3)&7)<<1 == (t>>2)&0xE == PS's mask at i=2t.
__device__ __forceinline__ int PS(int i)  { return i ^ ((i >> 3) & 0xE); }   // float2 index
__device__ __forceinline__ int PS4(int t) { return t ^ ((t >> 3) & 7);  }    // float4 index

// ---- linear-layout radix-4 butterflies (setup_filters only) ----
#define R4DIF_L(BUF) { \
  const float2 a = BUF[i0], b = BUF[i0 + q], c = BUF[i0 + 2 * q], d = BUF[i0 + 3 * q]; \
  const float2 t0 = cadd(a, c), t1 = csub(a, c), t2 = cadd(b, d), t3 = csub(b, d); \
  BUF[i0]         = cadd(t0, t2); \
  BUF[i0 + q]     = cmulf(make_float2(t1.x + t3.y, t1.y - t3.x), w1); \
  BUF[i0 + 2 * q] = cmulf(csub(t0, t2), w2); \
  BUF[i0 + 3 * q] = cmulf(make_float2(t1.x - t3.y, t1.y + t3.x), w3); }

// ---- swizzled-layout butterflies (main kernel): addresses a0..a3 precomputed ----
#define R4DIFS(BUF) { \
  const float2 a = BUF[a0], b = BUF[a1], c = BUF[a2], d = BUF[a3]; \
  const float2 t0 = cadd(a, c), t1 = csub(a, c), t2 = cadd(b, d), t3 = csub(b, d); \
  BUF[a0] = cadd(t0, t2); \
  BUF[a1] = cmulf(make_float2(t1.x + t3.y, t1.y - t3.x), w1); \
  BUF[a2] = cmulf(csub(t0, t2), w2); \
  BUF[a3] = cmulf(make_float2(t1.x - t3.y, t1.y + t3.x), w3); }

#define R4DITS(BUF) { \
  const float2 z0 = BUF[a0]; \
  const float2 z1 = cmulcf(BUF[a1], w1); \
  const float2 z2 = cmulcf(BUF[a2], w2); \
  const float2 z3 = cmulcf(BUF[a3], w3); \
  const float2 t0 = cadd(z0, z2), t1 = csub(z0, z2), t2 = cadd(z1, z3), u = csub(z1, z3); \
  BUF[a0] = cadd(t0, t2); \
  BUF[a1] = make_float2(t1.x - u.y, t1.y + u.x); \
  BUF[a2] = csub(t0, t2); \
  BUF[a3] = make_float2(t1.x + u.y, t1.y - u.x); }

// fused r2 + H-pointwise + r2inv on one float2-pair packed in a float4
__device__ __forceinline__ float4 midpair(float4 a, float4 h) {
  float2 u = make_float2(a.x + a.z, a.y + a.w);
  float2 v = make_float2(a.x - a.z, a.y - a.w);
  u = cmulf(u, make_float2(h.x, h.y));
  v = cmulf(v, make_float2(h.z, h.w));
  return make_float4(u.x + v.x, u.y + v.y, u.x - v.x, u.y - v.y);
}

// full Bluestein convolution on TWO swizzled buffers, 1024 threads
static __device__ void conv2(float2* A, float2* B, const float2* __restrict__ Hf) {
  const int tid = threadIdx.x;
  float4* A4f = reinterpret_cast<float4*>(A);
  float4* B4f = reinterpret_cast<float4*>(B);
  const float4* H4 = reinterpret_cast<const float4*>(Hf);
  #pragma unroll
  for (int s = 0; s < 6; ++s) {
    const int q = 2048 >> (2 * s);
    const int pq1 = PS(q), pq2 = PS(2 * q), pq3 = PS(3 * q);
    __syncthreads();
    #pragma unroll
    for (int r = 0; r < 2; ++r) {
      const int bid = tid + (r << 10);
      const int j   = bid & (q - 1);
      const int i0  = ((bid >> (11 - 2 * s)) << (13 - 2 * s)) + j;
      const int a0  = PS(i0), a1 = a0 ^ pq1, a2 = a0 ^ pq2, a3 = a0 ^ pq3;
      const float2 w1 = twf(j << (2 * s));
      const float2 w2 = cmulf(w1, w1);
      const float2 w3 = cmulf(w2, w1);
      R4DIFS(A) R4DIFS(B)
    }
  }
  __syncthreads();
  #pragma unroll
  for (int r = 0; r < 4; ++r) {
    const int p  = tid + (r << 10);
    const int pp = PS4(p);
    const float4 h = H4[p];
    A4f[pp] = midpair(A4f[pp], h);
    B4f[pp] = midpair(B4f[pp], h);
  }
  #pragma unroll
  for (int s = 5; s >= 0; --s) {
    const int q = 2048 >> (2 * s);
    const int pq1 = PS(q), pq2 = PS(2 * q), pq3 = PS(3 * q);
    __syncthreads();
    #pragma unroll
    for (int r = 0; r < 2; ++r) {
      const int bid = tid + (r << 10);
      const int j   = bid & (q - 1);
      const int i0  = ((bid >> (11 - 2 * s)) << (13 - 2 * s)) + j;
      const int a0  = PS(i0), a1 = a0 ^ pq1, a2 = a0 ^ pq2, a3 = a0 ^ pq3;
      const float2 w1 = twf(j << (2 * s));
      const float2 w2 = cmulf(w1, w1);
      const float2 w3 = cmulf(w2, w1);
      R4DITS(A) R4DITS(B)
    }
  }
  __syncthreads();
}

// single-buffer variant
static __device__ void conv1(float2* A, const float2* __restrict__ Hf) {
  const int tid = threadIdx.x;
  float4* A4f = reinterpret_cast<float4*>(A);
  const float4* H4 = reinterpret_cast<const float4*>(Hf);
  #pragma unroll
  for (int s = 0; s < 6; ++s) {
    const int q = 2048 >> (2 * s);
    const int pq1 = PS(q), pq2 = PS(2 * q), pq3 = PS(3 * q);
    __syncthreads();
    #pragma unroll
    for (int r = 0; r < 2; ++r) {
      const int bid = tid + (r << 10);
      const int j   = bid & (q - 1);
      const int i0  = ((bid >> (11 - 2 * s)) << (13 - 2 * s)) + j;
      const int a0  = PS(i0), a1 = a0 ^ pq1, a2 = a0 ^ pq2, a3 = a0 ^ pq3;
      const float2 w1 = twf(j << (2 * s));
      const float2 w2 = cmulf(w1, w1);
      const float2 w3 = cmulf(w2, w1);
      R4DIFS(A)
    }
  }
  __syncthreads();
  #pragma unroll
  for (int r = 0; r < 4; ++r) {
    const int p  = tid + (r << 10);
    const int pp = PS4(p);
    const float4 h = H4[p];
    A4f[pp] = midpair(A4f[pp], h);
  }
  #pragma unroll
  for (int s = 5; s >= 0; --s) {
    const int q = 2048 >> (2 * s);
    const int pq1 = PS(q), pq2 = PS(2 * q), pq3 = PS(3 * q);
    __syncthreads();
    #pragma unroll
    for (int r = 0; r < 2; ++r) {
      const int bid = tid + (r << 10);
      const int j   = bid & (q - 1);
      const int i0  = ((bid >> (11 - 2 * s)) << (13 - 2 * s)) + j;
      const int a0  = PS(i0), a1 = a0 ^ pq1, a2 = a0 ^ pq2, a3 = a0 ^ pq3;
      const float2 w1 = twf(j << (2 * s));
      const float2 w2 = cmulf(w1, w1);
      const float2 w3 = cmulf(w2, w1);
      R4DITS(A)
    }
  }
  __syncthreads();
}

// ---------------- setup: tables (fp64) + Bluestein filters (linear layout) ----------------
template <int NT>
static __device__ void fft_dif_tab(float2* buf, const float2* __restrict__ tw) {
  const int tid = threadIdx.x;
  for (int s = 0; s < 6; ++s) {
    const int q = 2048 >> (2 * s);
    __syncthreads();
    for (int r = 0; r < 2048 / NT; ++r) {
      const int bid = tid + r * NT;
      const int j   = bid & (q - 1);
      const int i0  = ((bid >> (11 - 2 * s)) << (13 - 2 * s)) + j;
      const int e   = j << (2 * s);
      const float2 w1 = tw[e], w2 = tw[2 * e], w3 = tw[3 * e];
      R4DIF_L(buf)
    }
  }
  __syncthreads();
  for (int r = 0; r < 4096 / NT; ++r) {
    const int i0 = (tid + r * NT) << 1;
    const float2 a = buf[i0], b = buf[i0 + 1];
    buf[i0] = cadd(a, b); buf[i0 + 1] = csub(a, b);
  }
  __syncthreads();
}

extern "C" __global__ void setup_tables(float2* ws) {
  const int idx = blockIdx.x * 512 + threadIdx.x;
  if (idx < 4096) {
    const long p = ((long)idx * idx) % 16382;      // j^2 mod 2*8191
    const double th = -M_PI * (double)p / 8191.0;
    double s, c; sincos(th, &s, &c);
    ws[WS_C + idx] = make_float2((float)c, (float)s);
  } else if (idx < 8192) {
    const int j = idx - 4096;
    const long p = ((long)j * j) % 16380;          // j^2 mod 2*8190
    const double th = M_PI * (double)p / 8190.0;
    double s, c; sincos(th, &s, &c);
    ws[WS_D + j] = make_float2((float)c, (float)s);
  } else if (idx < 16384) {
    const int j = idx - 8192;
    const double th = -M_PI * (double)j / 4096.0;  // e^{-2pi i j/8192}
    double s, c; sincos(th, &s, &c);
    ws[WS_TW + j] = make_float2((float)c, (float)s);
  }
}

extern "C" __global__ __launch_bounds__(512, 1) void setup_filters(float2* ws) {
  __shared__ __align__(16) float2 buf[M_];
  const float2* src = ws + (blockIdx.x == 0 ? WS_C : WS_D);
  float2*       dst = ws + (blockIdx.x == 0 ? WS_H1 : WS_H2);
  const float2* tw  = ws + WS_TW;
  for (int i = threadIdx.x; i < M_; i += 512) {
    float2 val = make_float2(0.f, 0.f);
    if (i != 4096) {                       // kernel support |j| <= 4095
      const int jj = (i <= 4095) ? i : (M_ - i);   // chirp is even in j
      const float2 e = src[jj];
      val = make_float2(e.x, -e.y);        // conj(chirp)
    }
    buf[i] = val;
  }
  fft_dif_tab<512>(buf, tw);
  const float sc = 1.0f / 8192.0f;         // fold IFFT scaling into the filter
  for (int i = threadIdx.x; i < M_; i += 512)
    dst[i] = make_float2(buf[i].x * sc, buf[i].y * sc);
}

// ---------------- projection kernel v3: depth-3 software pipeline, NT loads ----------------
// iter it = s*8 + g (s = input, g = row-group). Each iter: one 2-row chunk (1024 floats),
// lane covers floats [16*lane, 16*lane+16) -> 4 vf4 NT loads; reduce = 2-stage shfl.
#define PROJ_ISSUE(BUF, IT) { \
  const int s_ = (IT) >> 3, g_ = (IT) & 7; \
  const int l0_ = lbase + (wave << 1) + (g_ << 3); \
  const vf4* p_ = (s_ == 0 ? q4p : (s_ == 1 ? k4p : v4p)) + (((size_t)l0_) << 7) + (lane << 2); \
  BUF[0] = __builtin_nontemporal_load(p_ + 0); \
  BUF[1] = __builtin_nontemporal_load(p_ + 1); \
  BUF[2] = __builtin_nontemporal_load(p_ + 2); \
  BUF[3] = __builtin_nontemporal_load(p_ + 3); }

#define PROJ_REDUCE(BUF, IT) { \
  const int s_ = (IT) >> 3, g_ = (IT) & 7; \
  const int l0_ = lbase + (wave << 1) + (g_ << 3); \
  const float4 w0_ = (s_ == 0 ? wq0 : (s_ == 1 ? wk0 : wv0)); \
  const float4 w1_ = (s_ == 0 ? wq1 : (s_ == 1 ? wk1 : wv1)); \
  const float4 w2_ = (s_ == 0 ? wq2 : (s_ == 1 ? wk2 : wv2)); \
  const float4 w3_ = (s_ == 0 ? wq3 : (s_ == 1 ? wk3 : wv3)); \
  float f_ = BUF[0].x * w0_.x + BUF[0].y * w0_.y + BUF[0].z * w0_.z + BUF[0].w * w0_.w \
           + BUF[1].x * w1_.x + BUF[1].y * w1_.y + BUF[1].z * w1_.z + BUF[1].w * w1_.w \
           + BUF[2].x * w2_.x + BUF[2].y * w2_.y + BUF[2].z * w2_.z + BUF[2].w * w2_.w \
           + BUF[3].x * w3_.x + BUF[3].y * w3_.y + BUF[3].z * w3_.z + BUF[3].w * w3_.w; \
  f_ += __shfl_xor(f_, 1); f_ += __shfl_xor(f_, 2); \
  if (qt == 0) { \
    float* d_ = (s_ == 0 ? q_ws : (s_ == 1 ? k_ws : v_ws)) + (((size_t)(b8 + hh)) << 12) + l0_ + dl; \
    *d_ = f_ + (s_ == 0 ? bq0 : (s_ == 1 ? bk0 : bv0)); } }

extern "C" __global__ __launch_bounds__(256, 4)
void proj_kernel(const float* __restrict__ queries, const float* __restrict__ keys,
                 const float* __restrict__ values,
                 const float* __restrict__ Wq, const float* __restrict__ bq,
                 const float* __restrict__ Wk, const float* __restrict__ bk,
                 const float* __restrict__ Wv, const float* __restrict__ bv,
                 float* __restrict__ q_ws, float* __restrict__ k_ws,
                 float* __restrict__ v_ws)
{
  const int tid  = threadIdx.x;
  const int wave = tid >> 6;           // 0..3
  const int lane = tid & 63;
  const int qt   = lane & 3;           // d-quarter
  const int rr   = lane >> 2;          // 0..15
  const int hh   = rr & 7;             // head
  const int dl   = rr >> 3;            // row offset in chunk (0..1)
  const int blk  = blockIdx.x;         // 2048 blocks
  const int b    = blk >> 6;           // 0..31
  const int b8   = b * 8;
  const int lbase = (blk & 63) << 6;   // 0..4032 step 64

  const vf4* q4p = reinterpret_cast<const vf4*>(queries) + (size_t)b * 524288;
  const vf4* k4p = reinterpret_cast<const vf4*>(keys)    + (size_t)b * 524288;
  const vf4* v4p = reinterpret_cast<const vf4*>(values)  + (size_t)b * 524288;

  const float4* Wq4 = reinterpret_cast<const float4*>(Wq);
  const float4* Wk4 = reinterpret_cast<const float4*>(Wk);
  const float4* Wv4 = reinterpret_cast<const float4*>(Wv);
  const float4 wq0 = Wq4[qt * 4 + 0], wq1 = Wq4[qt * 4 + 1], wq2 = Wq4[qt * 4 + 2], wq3 = Wq4[qt * 4 + 3];
  const float4 wk0 = Wk4[qt * 4 + 0], wk1 = Wk4[qt * 4 + 1], wk2 = Wk4[qt * 4 + 2], wk3 = Wk4[qt * 4 + 3];
  const float4 wv0 = Wv4[qt * 4 + 0], wv1 = Wv4[qt * 4 + 1], wv2 = Wv4[qt * 4 + 2], wv3 = Wv4[qt * 4 + 3];
  const float bq0 = bq[0], bk0 = bk[0], bv0 = bv[0];

  vf4 bA[4], bB[4], bC[4];
  PROJ_ISSUE(bA, 0)
  PROJ_ISSUE(bB, 1)
  #pragma unroll
  for (int it = 0; it < 24; ++it) {
    const int nx = it + 2;
    if (nx < 24) {
      if      (nx % 3 == 0) { PROJ_ISSUE(bA, nx) }
      else if (nx % 3 == 1) { PROJ_ISSUE(bB, nx) }
      else                  { PROJ_ISSUE(bC, nx) }
    }
    if      (it % 3 == 0) { PROJ_REDUCE(bA, it) }
    else if (it % 3 == 1) { PROJ_REDUCE(bB, it) }
    else                  { PROJ_REDUCE(bC, it) }
  }
}

// ---------------- main kernel: CZT scores + topk + softmax + gather (swizzled LDS) --------
extern "C" __global__ __launch_bounds__(1024, 1)
void autocorr_main(const float2* __restrict__ ws,
                   const float* __restrict__ q_ws, const float* __restrict__ k_ws,
                   const float* __restrict__ v_ws, float* __restrict__ outp)
{
  __shared__ __align__(16) float2 bufA[M_];   // 64 KB (K path, then inverse-CZT)
  __shared__ __align__(16) float2 bufB[M_];   // 64 KB (Q path)
  __shared__ float  v_lds[L_];                // 16 KB (linear, no swizzle)
  __shared__ float  cand_v[16 * KK];
  __shared__ int    cand_i[16 * KK];
  __shared__ float  w_sh[KK];
  __shared__ int    i_sh[KK];

  const int tid = threadIdx.x;
  const int bh  = blockIdx.x;

  const float2* c_t = ws + WS_C;
  const float2* d_t = ws + WS_D;
  const float2* H1  = ws + WS_H1;
  const float2* H2  = ws + WS_H2;
  const float* qrow = q_ws + ((size_t)bh << 12);
  const float* krow = k_ws + ((size_t)bh << 12);
  const float* vrow = v_ws + ((size_t)bh << 12);

  // v into LDS; chirp-premultiplied k (bufA) / q (bufB) at swizzled slots; zero-pad linear
  // (the pad region [4096,8192) is PS/PS4-invariant as a set, so linear zeroing is correct)
  {
    const float4 v4 = reinterpret_cast<const float4*>(vrow)[tid];
    reinterpret_cast<float4*>(v_lds)[tid] = v4;
    const float4 k4 = reinterpret_cast<const float4*>(krow)[tid];
    const float4 q4 = reinterpret_cast<const float4*>(qrow)[tid];
    const float4 c01 = reinterpret_cast<const float4*>(c_t)[2 * tid];
    const float4 c23 = reinterpret_cast<const float4*>(c_t)[2 * tid + 1];
    float4* A4 = reinterpret_cast<float4*>(bufA);
    float4* B4 = reinterpret_cast<float4*>(bufB);
    const int p0 = PS4(2 * tid), p1 = PS4(2 * tid + 1);
    A4[p0] = make_float4(k4.x * c01.x, k4.x * c01.y, k4.y * c01.z, k4.y * c01.w);
    A4[p1] = make_float4(k4.z * c23.x, k4.z * c23.y, k4.w * c23.z, k4.w * c23.w);
    B4[p0] = make_float4(q4.x * c01.x, q4.x * c01.y, q4.y * c01.z, q4.y * c01.w);
    B4[p1] = make_float4(q4.z * c23.x, q4.z * c23.y, q4.w * c23.z, q4.w * c23.w);
    const float4 z = make_float4(0.f, 0.f, 0.f, 0.f);
    A4[2048 + tid] = z; A4[3072 + tid] = z;
    B4[2048 + tid] = z; B4[3072 + tid] = z;
  }

  // ------- fused forward CZT for K (A) and Q (B) -------
  conv2(bufA, bufB, H1);

  // ------- F = (c.Q) * conj(c.K); build g.d into bufA (inverse-CZT input) -------
  #pragma unroll
  for (int r = 0; r < 4; ++r) {
    const int m  = tid + (r << 10);
    const int pm = PS(m);
    const float2 cc = c_t[m];
    const float2 K = cmulf(cc, bufA[pm]);
    const float2 Q = cmulf(cc, bufB[pm]);
    const float2 F = cmulcf(Q, K);
    float2 g;
    if (m == 0 || m == 4095) g = make_float2(F.x, 0.f);   // DC/Nyquist: Im dropped
    else                     g = make_float2(2.f * F.x, 2.f * F.y);
    bufA[pm] = cmulf(g, d_t[m]);
  }
  #pragma unroll
  for (int r = 4; r < 8; ++r) bufA[tid + (r << 10)] = make_float2(0.f, 0.f);

  // ------- inverse via irfft_8190 semantics: y_t = Re(d_t * IFFT(FFT(g.d) . H2)[t]) -------
  conv1(bufA, H2);

  // ---------------- scores + per-wave top-45 ----------------
  const float SCALE = (float)(1.0 / (8190.0 * 4096.0));   // /8190 (irfft) then /4096 (L)
  float svv[4]; int sii[4];
  #pragma unroll
  for (int r = 0; r < 4; ++r) {
    const int t = tid + (r << 10);
    const float2 Z = cmulf(d_t[t], bufA[PS(t)]);
    svv[r] = Z.x * SCALE;
    sii[r] = t;
  }
  const int lane = tid & 63, wv = tid >> 6;   // 16 waves
  for (int it = 0; it < KK; ++it) {
    float bvv = -FLT_MAX; int bii = 0x7fffffff;
    #pragma unroll
    for (int c = 0; c < 4; ++c)
      if (svv[c] > bvv || (svv[c] == bvv && sii[c] < bii)) { bvv = svv[c]; bii = sii[c]; }
    #pragma unroll
    for (int off = 1; off < 64; off <<= 1) {
      const float ov = __shfl_xor(bvv, off);
      const int   oi = __shfl_xor(bii, off);
      if (ov > bvv || (ov == bvv && oi < bii)) { bvv = ov; bii = oi; }
    }
    #pragma unroll
    for (int c = 0; c < 4; ++c) if (sii[c] == bii) svv[c] = -FLT_MAX;
    if (lane == 0) { cand_v[wv * KK + it] = bvv; cand_i[wv * KK + it] = bii; }
  }
  __syncthreads();

  // ---------------- merge 16x45 + softmax (wave 0) ----------------
  if (tid < 64) {
    float mv[12]; int mi[12];
    #pragma unroll
    for (int c = 0; c < 12; ++c) {
      const int id = tid + 64 * c;
      if (id < 16 * KK) { mv[c] = cand_v[id]; mi[c] = cand_i[id]; }
      else              { mv[c] = -FLT_MAX;   mi[c] = 0x7fffffff; }
    }
    float m0 = 0.f, sum = 0.f, myv = -FLT_MAX; int myi = 0;
    for (int it = 0; it < KK; ++it) {
      float bvv = -FLT_MAX; int bii = 0x7fffffff;
      #pragma unroll
      for (int c = 0; c < 12; ++c)
        if (mv[c] > bvv || (mv[c] == bvv && mi[c] < bii)) { bvv = mv[c]; bii = mi[c]; }
      #pragma unroll
      for (int off = 1; off < 64; off <<= 1) {
        const float ov = __shfl_xor(bvv, off);
        const int   oi = __shfl_xor(bii, off);
        if (ov > bvv || (ov == bvv && oi < bii)) { bvv = ov; bii = oi; }
      }
      if (it == 0) m0 = bvv;
      sum += expf(bvv - m0);               // identical on all lanes
      if (tid == it) { myv = bvv; myi = bii; }
      #pragma unroll
      for (int c = 0; c < 12; ++c) if (mi[c] == bii) mv[c] = -FLT_MAX;
    }
    if (tid < KK) { w_sh[tid] = expf(myv - m0) / sum; i_sh[tid] = myi; }
  }
  __syncthreads();

  // ---------------- gather: out[t] = sum_j w_j * v[(idx_j + t) & 4095] ------------
  {
    float acc[4] = {0, 0, 0, 0};
    for (int j = 0; j < KK; ++j) {
      const float wj = w_sh[j];
      const int   bse = i_sh[j] + tid;
      #pragma unroll
      for (int r = 0; r < 4; ++r)
        acc[r] = fmaf(wj, v_lds[(bse + (r << 10)) & (L_ - 1)], acc[r]);
    }
    float* op = outp + ((size_t)bh << 12);
    #pragma unroll
    for (int r = 0; r < 4; ++r) op[tid + (r << 10)] = acc[r];
  }
}

extern "C" void kernel_launch(void* const* d_in, const int* in_sizes, int n_in,
                              void* d_out, int out_size, void* d_ws, size_t ws_size,
                              hipStream_t stream) {
  const float* queries = (const float*)d_in[0];
  const float* keys    = (const float*)d_in[1];
  const float* values  = (const float*)d_in[2];
  const float* Wq = (const float*)d_in[3];
  const float* bq = (const float*)d_in[4];
  const float* Wk = (const float*)d_in[5];
  const float* bk = (const float*)d_in[6];
  const float* Wv = (const float*)d_in[7];
  const float* bv = (const float*)d_in[8];
  float2* ws = (float2*)d_ws;
  float* q_ws = (float*)d_ws + 2 * WS_QKV;
  float* k_ws = q_ws + (1 << 20);
  float* v_ws = k_ws + (1 << 20);
  float* out = (float*)d_out;

  hipLaunchKernelGGL(setup_tables,  dim3(32), dim3(512), 0, stream, ws);
  hipLaunchKernelGGL(setup_filters, dim3(2),  dim3(512), 0, stream, ws);
  hipLaunchKernelGGL(proj_kernel,   dim3(2048), dim3(256), 0, stream,
                     queries, keys, values, Wq, bq, Wk, bk, Wv, bv, q_ws, k_ws, v_ws);
  hipLaunchKernelGGL(autocorr_main, dim3(256), dim3(1024), 0, stream,
                     ws, q_ws, k_ws, v_ws, out);
}

// Round 11
// 339.856 us; speedup vs baseline: 1.1679x; 1.1679x over previous
//
#include <hip/hip_runtime.h>
#include <math.h>
#include <float.h>

#define L_   4096
#define M_   8192
#define H_   8
#define D_   64
#define KK   45          // 5 * ceil(ln(4096))

// ws layout in float2 units
#define WS_C   0         // c[4096]  : e^{-i pi j^2 / 8191}
#define WS_D   4096      // d[4096]  : e^{+i pi j^2 / 8190}
#define WS_TW  8192      // tw[8192] : e^{-2 pi i j / 8192} (fp64-accurate; setup_filters only)
#define WS_H1  16384     // H1s[8192]: DIF-FFT(conj-chirp c), pre-scaled 1/8192, digit-reversed
#define WS_H2  24576     // H2s[8192]: same for d
#define WS_QKV 32768     // float2 offset where staged q/k/v planes start
// tables: 256 KB; then q/k/v planes: 3 x 1M floats = 12 MB

__device__ __forceinline__ float2 cadd(float2 a, float2 b) { return make_float2(a.x + b.x, a.y + b.y); }
__device__ __forceinline__ float2 csub(float2 a, float2 b) { return make_float2(a.x - b.x, a.y - b.y); }
__device__ __forceinline__ float2 cmulf(float2 a, float2 b) {
  return make_float2(a.x * b.x - a.y * b.y, a.x * b.y + a.y * b.x);
}
__device__ __forceinline__ float2 cmulcf(float2 a, float2 b) {  // a * conj(b)
  return make_float2(a.x * b.x + a.y * b.y, a.y * b.x - a.x * b.y);
}

// register twiddle: e^{-2 pi i e / 8192}, e in [0, 2048)
__device__ __forceinline__ float2 twf(int e) {
  float s, c;
  __sincosf((float)e * -7.66990394e-4f, &s, &c);   // -2*pi/8192
  return make_float2(c, s);
}

#define R4DIF(BUF) { \
  const float2 a = BUF[i0], b = BUF[i0 + q], c = BUF[i0 + 2 * q], d = BUF[i0 + 3 * q]; \
  const float2 t0 = cadd(a, c), t1 = csub(a, c), t2 = cadd(b, d), t3 = csub(b, d); \
  BUF[i0]         = cadd(t0, t2); \
  BUF[i0 + q]     = cmulf(make_float2(t1.x + t3.y, t1.y - t3.x), w1); \
  BUF[i0 + 2 * q] = cmulf(csub(t0, t2), w2); \
  BUF[i0 + 3 * q] = cmulf(make_float2(t1.x - t3.y, t1.y + t3.x), w3); }

#define R4DIT(BUF) { \
  const float2 z0 = BUF[i0]; \
  const float2 z1 = cmulcf(BUF[i0 + q],     w1); \
  const float2 z2 = cmulcf(BUF[i0 + 2 * q], w2); \
  const float2 z3 = cmulcf(BUF[i0 + 3 * q], w3); \
  const float2 t0 = cadd(z0, z2), t1 = csub(z0, z2), t2 = cadd(z1, z3), u = csub(z1, z3); \
  BUF[i0]         = cadd(t0, t2); \
  BUF[i0 + q]     = make_float2(t1.x - u.y, t1.y + u.x); \
  BUF[i0 + 2 * q] = csub(t0, t2); \
  BUF[i0 + 3 * q] = make_float2(t1.x + u.y, t1.y - u.x); }

// fused r2 + H-pointwise + r2inv on one float2-pair packed in a float4
__device__ __forceinline__ float4 midpair(float4 a, float4 h) {
  float2 u = make_float2(a.x + a.z, a.y + a.w);
  float2 v = make_float2(a.x - a.z, a.y - a.w);
  u = cmulf(u, make_float2(h.x, h.y));
  v = cmulf(v, make_float2(h.z, h.w));
  return make_float4(u.x + v.x, u.y + v.y, u.x - v.x, u.y - v.y);
}

// full Bluestein convolution pass on TWO buffers (shared twiddles), 1024 threads
static __device__ void conv2(float2* A, float2* B, const float2* __restrict__ Hf) {
  const int tid = threadIdx.x;
  #pragma unroll
  for (int s = 0; s < 6; ++s) {
    const int q = 2048 >> (2 * s);
    __syncthreads();
    #pragma unroll
    for (int r = 0; r < 2; ++r) {
      const int bid = tid + (r << 10);
      const int j   = bid & (q - 1);
      const int i0  = ((bid >> (11 - 2 * s)) << (13 - 2 * s)) + j;
      const float2 w1 = twf(j << (2 * s));
      const float2 w2 = cmulf(w1, w1);
      const float2 w3 = cmulf(w2, w1);
      R4DIF(A) R4DIF(B)
    }
  }
  __syncthreads();
  #pragma unroll
  for (int r = 0; r < 4; ++r) {
    const int p = tid + (r << 10);
    const float4 h = reinterpret_cast<const float4*>(Hf)[p];
    reinterpret_cast<float4*>(A)[p] = midpair(reinterpret_cast<float4*>(A)[p], h);
    reinterpret_cast<float4*>(B)[p] = midpair(reinterpret_cast<float4*>(B)[p], h);
  }
  #pragma unroll
  for (int s = 5; s >= 0; --s) {
    const int q = 2048 >> (2 * s);
    __syncthreads();
    #pragma unroll
    for (int r = 0; r < 2; ++r) {
      const int bid = tid + (r << 10);
      const int j   = bid & (q - 1);
      const int i0  = ((bid >> (11 - 2 * s)) << (13 - 2 * s)) + j;
      const float2 w1 = twf(j << (2 * s));
      const float2 w2 = cmulf(w1, w1);
      const float2 w3 = cmulf(w2, w1);
      R4DIT(A) R4DIT(B)
    }
  }
  __syncthreads();
}

// single-buffer variant
static __device__ void conv1(float2* A, const float2* __restrict__ Hf) {
  const int tid = threadIdx.x;
  #pragma unroll
  for (int s = 0; s < 6; ++s) {
    const int q = 2048 >> (2 * s);
    __syncthreads();
    #pragma unroll
    for (int r = 0; r < 2; ++r) {
      const int bid = tid + (r << 10);
      const int j   = bid & (q - 1);
      const int i0  = ((bid >> (11 - 2 * s)) << (13 - 2 * s)) + j;
      const float2 w1 = twf(j << (2 * s));
      const float2 w2 = cmulf(w1, w1);
      const float2 w3 = cmulf(w2, w1);
      R4DIF(A)
    }
  }
  __syncthreads();
  #pragma unroll
  for (int r = 0; r < 4; ++r) {
    const int p = tid + (r << 10);
    const float4 h = reinterpret_cast<const float4*>(Hf)[p];
    reinterpret_cast<float4*>(A)[p] = midpair(reinterpret_cast<float4*>(A)[p], h);
  }
  #pragma unroll
  for (int s = 5; s >= 0; --s) {
    const int q = 2048 >> (2 * s);
    __syncthreads();
    #pragma unroll
    for (int r = 0; r < 2; ++r) {
      const int bid = tid + (r << 10);
      const int j   = bid & (q - 1);
      const int i0  = ((bid >> (11 - 2 * s)) << (13 - 2 * s)) + j;
      const float2 w1 = twf(j << (2 * s));
      const float2 w2 = cmulf(w1, w1);
      const float2 w3 = cmulf(w2, w1);
      R4DIT(A)
    }
  }
  __syncthreads();
}

// ---------------- setup: tables (fp64) + Bluestein filters ----------------
// table-twiddle DIF kept ONLY for setup_filters (must match conv's digit-reversed order)
template <int NT>
static __device__ void fft_dif_tab(float2* buf, const float2* __restrict__ tw) {
  const int tid = threadIdx.x;
  for (int s = 0; s < 6; ++s) {
    const int q = 2048 >> (2 * s);
    __syncthreads();
    for (int r = 0; r < 2048 / NT; ++r) {
      const int bid = tid + r * NT;
      const int j   = bid & (q - 1);
      const int i0  = ((bid >> (11 - 2 * s)) << (13 - 2 * s)) + j;
      const int e   = j << (2 * s);
      const float2 w1 = tw[e], w2 = tw[2 * e], w3 = tw[3 * e];
      R4DIF(buf)
    }
  }
  __syncthreads();
  for (int r = 0; r < 4096 / NT; ++r) {
    const int i0 = (tid + r * NT) << 1;
    const float2 a = buf[i0], b = buf[i0 + 1];
    buf[i0] = cadd(a, b); buf[i0 + 1] = csub(a, b);
  }
  __syncthreads();
}

extern "C" __global__ void setup_tables(float2* ws) {
  const int idx = blockIdx.x * 512 + threadIdx.x;
  if (idx < 4096) {
    const long p = ((long)idx * idx) % 16382;      // j^2 mod 2*8191
    const double th = -M_PI * (double)p / 8191.0;
    double s, c; sincos(th, &s, &c);
    ws[WS_C + idx] = make_float2((float)c, (float)s);
  } else if (idx < 8192) {
    const int j = idx - 4096;
    const long p = ((long)j * j) % 16380;          // j^2 mod 2*8190
    const double th = M_PI * (double)p / 8190.0;
    double s, c; sincos(th, &s, &c);
    ws[WS_D + j] = make_float2((float)c, (float)s);
  } else if (idx < 16384) {
    const int j = idx - 8192;
    const double th = -M_PI * (double)j / 4096.0;  // e^{-2pi i j/8192}
    double s, c; sincos(th, &s, &c);
    ws[WS_TW + j] = make_float2((float)c, (float)s);
  }
}

extern "C" __global__ __launch_bounds__(512, 1) void setup_filters(float2* ws) {
  __shared__ __align__(16) float2 buf[M_];
  const float2* src = ws + (blockIdx.x == 0 ? WS_C : WS_D);
  float2*       dst = ws + (blockIdx.x == 0 ? WS_H1 : WS_H2);
  const float2* tw  = ws + WS_TW;
  for (int i = threadIdx.x; i < M_; i += 512) {
    float2 val = make_float2(0.f, 0.f);
    if (i != 4096) {                       // kernel support |j| <= 4095
      const int jj = (i <= 4095) ? i : (M_ - i);   // chirp is even in j
      const float2 e = src[jj];
      val = make_float2(e.x, -e.y);        // conj(chirp)
    }
    buf[i] = val;
  }
  fft_dif_tab<512>(buf, tw);
  const float sc = 1.0f / 8192.0f;         // fold IFFT scaling into the filter
  for (int i = threadIdx.x; i < M_; i += 512)
    dst[i] = make_float2(buf[i].x * sc, buf[i].y * sc);
}

// ---------------- projection kernel v3b: depth-3 software pipeline, PLAIN loads ----------
// iter it = s*8 + g (s = input, g = row-group). Each iter: one 2-row chunk (1024 floats),
// lane covers floats [16*lane, 16*lane+16) -> 4 float4 loads; reduce = 2-stage shfl.
#define PROJ_ISSUE(BUF, IT) { \
  const int s_ = (IT) >> 3, g_ = (IT) & 7; \
  const int l0_ = lbase + (wave << 1) + (g_ << 3); \
  const float4* p_ = (s_ == 0 ? q4p : (s_ == 1 ? k4p : v4p)) + (((size_t)l0_) << 7) + (lane << 2); \
  BUF[0] = p_[0]; \
  BUF[1] = p_[1]; \
  BUF[2] = p_[2]; \
  BUF[3] = p_[3]; }

#define PROJ_REDUCE(BUF, IT) { \
  const int s_ = (IT) >> 3, g_ = (IT) & 7; \
  const int l0_ = lbase + (wave << 1) + (g_ << 3); \
  const float4 w0_ = (s_ == 0 ? wq0 : (s_ == 1 ? wk0 : wv0)); \
  const float4 w1_ = (s_ == 0 ? wq1 : (s_ == 1 ? wk1 : wv1)); \
  const float4 w2_ = (s_ == 0 ? wq2 : (s_ == 1 ? wk2 : wv2)); \
  const float4 w3_ = (s_ == 0 ? wq3 : (s_ == 1 ? wk3 : wv3)); \
  float f_ = BUF[0].x * w0_.x + BUF[0].y * w0_.y + BUF[0].z * w0_.z + BUF[0].w * w0_.w \
           + BUF[1].x * w1_.x + BUF[1].y * w1_.y + BUF[1].z * w1_.z + BUF[1].w * w1_.w \
           + BUF[2].x * w2_.x + BUF[2].y * w2_.y + BUF[2].z * w2_.z + BUF[2].w * w2_.w \
           + BUF[3].x * w3_.x + BUF[3].y * w3_.y + BUF[3].z * w3_.z + BUF[3].w * w3_.w; \
  f_ += __shfl_xor(f_, 1); f_ += __shfl_xor(f_, 2); \
  if (qt == 0) { \
    float* d_ = (s_ == 0 ? q_ws : (s_ == 1 ? k_ws : v_ws)) + (((size_t)(b8 + hh)) << 12) + l0_ + dl; \
    *d_ = f_ + (s_ == 0 ? bq0 : (s_ == 1 ? bk0 : bv0)); } }

extern "C" __global__ __launch_bounds__(256, 4)
void proj_kernel(const float* __restrict__ queries, const float* __restrict__ keys,
                 const float* __restrict__ values,
                 const float* __restrict__ Wq, const float* __restrict__ bq,
                 const float* __restrict__ Wk, const float* __restrict__ bk,
                 const float* __restrict__ Wv, const float* __restrict__ bv,
                 float* __restrict__ q_ws, float* __restrict__ k_ws,
                 float* __restrict__ v_ws)
{
  const int tid  = threadIdx.x;
  const int wave = tid >> 6;           // 0..3
  const int lane = tid & 63;
  const int qt   = lane & 3;           // d-quarter
  const int rr   = lane >> 2;          // 0..15
  const int hh   = rr & 7;             // head
  const int dl   = rr >> 3;            // row offset in chunk (0..1)
  const int blk  = blockIdx.x;         // 2048 blocks
  const int b    = blk >> 6;           // 0..31
  const int b8   = b * 8;
  const int lbase = (blk & 63) << 6;   // 0..4032 step 64

  const float4* q4p = reinterpret_cast<const float4*>(queries) + (size_t)b * 524288;
  const float4* k4p = reinterpret_cast<const float4*>(keys)    + (size_t)b * 524288;
  const float4* v4p = reinterpret_cast<const float4*>(values)  + (size_t)b * 524288;

  const float4* Wq4 = reinterpret_cast<const float4*>(Wq);
  const float4* Wk4 = reinterpret_cast<const float4*>(Wk);
  const float4* Wv4 = reinterpret_cast<const float4*>(Wv);
  const float4 wq0 = Wq4[qt * 4 + 0], wq1 = Wq4[qt * 4 + 1], wq2 = Wq4[qt * 4 + 2], wq3 = Wq4[qt * 4 + 3];
  const float4 wk0 = Wk4[qt * 4 + 0], wk1 = Wk4[qt * 4 + 1], wk2 = Wk4[qt * 4 + 2], wk3 = Wk4[qt * 4 + 3];
  const float4 wv0 = Wv4[qt * 4 + 0], wv1 = Wv4[qt * 4 + 1], wv2 = Wv4[qt * 4 + 2], wv3 = Wv4[qt * 4 + 3];
  const float bq0 = bq[0], bk0 = bk[0], bv0 = bv[0];

  float4 bA[4], bB[4], bC[4];
  PROJ_ISSUE(bA, 0)
  PROJ_ISSUE(bB, 1)
  #pragma unroll
  for (int it = 0; it < 24; ++it) {
    const int nx = it + 2;
    if (nx < 24) {
      if      (nx % 3 == 0) { PROJ_ISSUE(bA, nx) }
      else if (nx % 3 == 1) { PROJ_ISSUE(bB, nx) }
      else                  { PROJ_ISSUE(bC, nx) }
    }
    if      (it % 3 == 0) { PROJ_REDUCE(bA, it) }
    else if (it % 3 == 1) { PROJ_REDUCE(bB, it) }
    else                  { PROJ_REDUCE(bC, it) }
  }
}

// ---------------- main kernel: CZT scores + topk + softmax + gather (linear LDS) --------
extern "C" __global__ __launch_bounds__(1024, 1)
void autocorr_main(const float2* __restrict__ ws,
                   const float* __restrict__ q_ws, const float* __restrict__ k_ws,
                   const float* __restrict__ v_ws, float* __restrict__ outp)
{
  __shared__ __align__(16) float2 bufA[M_];   // 64 KB (K path, then inverse-CZT)
  __shared__ __align__(16) float2 bufB[M_];   // 64 KB (Q path)
  __shared__ float  v_lds[L_];                // 16 KB
  __shared__ float  cand_v[16 * KK];
  __shared__ int    cand_i[16 * KK];
  __shared__ float  w_sh[KK];
  __shared__ int    i_sh[KK];

  const int tid = threadIdx.x;
  const int bh  = blockIdx.x;

  const float2* c_t = ws + WS_C;
  const float2* d_t = ws + WS_D;
  const float2* H1  = ws + WS_H1;
  const float2* H2  = ws + WS_H2;
  const float* qrow = q_ws + ((size_t)bh << 12);
  const float* krow = k_ws + ((size_t)bh << 12);
  const float* vrow = v_ws + ((size_t)bh << 12);

  // v into LDS; chirp-premultiplied k (bufA) / q (bufB); zero-pad 4096..8191
  {
    const float4 v4 = reinterpret_cast<const float4*>(vrow)[tid];
    reinterpret_cast<float4*>(v_lds)[tid] = v4;
    const float4 k4 = reinterpret_cast<const float4*>(krow)[tid];
    const float4 q4 = reinterpret_cast<const float4*>(qrow)[tid];
    const float4 c01 = reinterpret_cast<const float4*>(c_t)[2 * tid];
    const float4 c23 = reinterpret_cast<const float4*>(c_t)[2 * tid + 1];
    float4* A4 = reinterpret_cast<float4*>(bufA);
    float4* B4 = reinterpret_cast<float4*>(bufB);
    A4[2 * tid]     = make_float4(k4.x * c01.x, k4.x * c01.y, k4.y * c01.z, k4.y * c01.w);
    A4[2 * tid + 1] = make_float4(k4.z * c23.x, k4.z * c23.y, k4.w * c23.z, k4.w * c23.w);
    B4[2 * tid]     = make_float4(q4.x * c01.x, q4.x * c01.y, q4.y * c01.z, q4.y * c01.w);
    B4[2 * tid + 1] = make_float4(q4.z * c23.x, q4.z * c23.y, q4.w * c23.z, q4.w * c23.w);
    const float4 z = make_float4(0.f, 0.f, 0.f, 0.f);
    A4[2048 + tid] = z; A4[3072 + tid] = z;
    B4[2048 + tid] = z; B4[3072 + tid] = z;
  }

  // ------- fused forward CZT for K (A) and Q (B) -------
  conv2(bufA, bufB, H1);

  // ------- F = (c.Q) * conj(c.K); build g.d into bufA (inverse-CZT input) -------
  #pragma unroll
  for (int r = 0; r < 4; ++r) {
    const int m = tid + (r << 10);
    const float2 cc = c_t[m];
    const float2 K = cmulf(cc, bufA[m]);
    const float2 Q = cmulf(cc, bufB[m]);
    const float2 F = cmulcf(Q, K);
    float2 g;
    if (m == 0 || m == 4095) g = make_float2(F.x, 0.f);   // DC/Nyquist: Im dropped
    else                     g = make_float2(2.f * F.x, 2.f * F.y);
    bufA[m] = cmulf(g, d_t[m]);
  }
  #pragma unroll
  for (int r = 4; r < 8; ++r) bufA[tid + (r << 10)] = make_float2(0.f, 0.f);

  // ------- inverse via irfft_8190 semantics: y_t = Re(d_t * IFFT(FFT(g.d) . H2)[t]) -------
  conv1(bufA, H2);

  // ---------------- scores + per-wave top-45 ----------------
  const float SCALE = (float)(1.0 / (8190.0 * 4096.0));   // /8190 (irfft) then /4096 (L)
  float svv[4]; int sii[4];
  #pragma unroll
  for (int r = 0; r < 4; ++r) {
    const int t = tid + (r << 10);
    const float2 Z = cmulf(d_t[t], bufA[t]);
    svv[r] = Z.x * SCALE;
    sii[r] = t;
  }
  const int lane = tid & 63, wv = tid >> 6;   // 16 waves
  for (int it = 0; it < KK; ++it) {
    float bvv = -FLT_MAX; int bii = 0x7fffffff;
    #pragma unroll
    for (int c = 0; c < 4; ++c)
      if (svv[c] > bvv || (svv[c] == bvv && sii[c] < bii)) { bvv = svv[c]; bii = sii[c]; }
    #pragma unroll
    for (int off = 1; off < 64; off <<= 1) {
      const float ov = __shfl_xor(bvv, off);
      const int   oi = __shfl_xor(bii, off);
      if (ov > bvv || (ov == bvv && oi < bii)) { bvv = ov; bii = oi; }
    }
    #pragma unroll
    for (int c = 0; c < 4; ++c) if (sii[c] == bii) svv[c] = -FLT_MAX;
    if (lane == 0) { cand_v[wv * KK + it] = bvv; cand_i[wv * KK + it] = bii; }
  }
  __syncthreads();

  // ---------------- merge 16x45 + softmax (wave 0) ----------------
  if (tid < 64) {
    float mv[12]; int mi[12];
    #pragma unroll
    for (int c = 0; c < 12; ++c) {
      const int id = tid + 64 * c;
      if (id < 16 * KK) { mv[c] = cand_v[id]; mi[c] = cand_i[id]; }
      else              { mv[c] = -FLT_MAX;   mi[c] = 0x7fffffff; }
    }
    float m0 = 0.f, sum = 0.f, myv = -FLT_MAX; int myi = 0;
    for (int it = 0; it < KK; ++it) {
      float bvv = -FLT_MAX; int bii = 0x7fffffff;
      #pragma unroll
      for (int c = 0; c < 12; ++c)
        if (mv[c] > bvv || (mv[c] == bvv && mi[c] < bii)) { bvv = mv[c]; bii = mi[c]; }
      #pragma unroll
      for (int off = 1; off < 64; off <<= 1) {
        const float ov = __shfl_xor(bvv, off);
        const int   oi = __shfl_xor(bii, off);
        if (ov > bvv || (ov == bvv && oi < bii)) { bvv = ov; bii = oi; }
      }
      if (it == 0) m0 = bvv;
      sum += expf(bvv - m0);               // identical on all lanes
      if (tid == it) { myv = bvv; myi = bii; }
      #pragma unroll
      for (int c = 0; c < 12; ++c) if (mi[c] == bii) mv[c] = -FLT_MAX;
    }
    if (tid < KK) { w_sh[tid] = expf(myv - m0) / sum; i_sh[tid] = myi; }
  }
  __syncthreads();

  // ---------------- gather: out[t] = sum_j w_j * v[(idx_j + t) & 4095] ------------
  {
    float acc[4] = {0, 0, 0, 0};
    for (int j = 0; j < KK; ++j) {
      const float wj = w_sh[j];
      const int   bse = i_sh[j] + tid;
      #pragma unroll
      for (int r = 0; r < 4; ++r)
        acc[r] = fmaf(wj, v_lds[(bse + (r << 10)) & (L_ - 1)], acc[r]);
    }
    float* op = outp + ((size_t)bh << 12);
    #pragma unroll
    for (int r = 0; r < 4; ++r) op[tid + (r << 10)] = acc[r];
  }
}

extern "C" void kernel_launch(void* const* d_in, const int* in_sizes, int n_in,
                              void* d_out, int out_size, void* d_ws, size_t ws_size,
                              hipStream_t stream) {
  const float* queries = (const float*)d_in[0];
  const float* keys    = (const float*)d_in[1];
  const float* values  = (const float*)d_in[2];
  const float* Wq = (const float*)d_in[3];
  const float* bq = (const float*)d_in[4];
  const float* Wk = (const float*)d_in[5];
  const float* bk = (const float*)d_in[6];
  const float* Wv = (const float*)d_in[7];
  const float* bv = (const float*)d_in[8];
  float2* ws = (float2*)d_ws;
  float* q_ws = (float*)d_ws + 2 * WS_QKV;
  float* k_ws = q_ws + (1 << 20);
  float* v_ws = k_ws + (1 << 20);
  float* out = (float*)d_out;

  hipLaunchKernelGGL(setup_tables,  dim3(32), dim3(512), 0, stream, ws);
  hipLaunchKernelGGL(setup_filters, dim3(2),  dim3(512), 0, stream, ws);
  hipLaunchKernelGGL(proj_kernel,   dim3(2048), dim3(256), 0, stream,
                     queries, keys, values, Wq, bq, Wk, bk, Wv, bv, q_ws, k_ws, v_ws);
  hipLaunchKernelGGL(autocorr_main, dim3(256), dim3(1024), 0, stream,
                     ws, q_ws, k_ws, v_ws, out);
}